// Round 5
// baseline (61592.590 us; speedup 1.0000x reference)
//
#include <hip/hip_runtime.h>

typedef unsigned int u32;
typedef unsigned short u16;
typedef _Float16 f16;
typedef _Float16 f16x2 __attribute__((ext_vector_type(2)));
typedef _Float16 f16x4 __attribute__((ext_vector_type(4)));

#define T_SEQ 32768

// ---------------- ws layout (bytes) ----------------
static const size_t OFF_DT   = 0;         // u32 dtype flag (1 = f32 inputs)
static const size_t OFF_FLG  = 1024;      // u32[128] (legacy, kept zeroed)
static const size_t OFF_MAP  = 4096;      // int [T]
static const size_t OFF_H1G  = 135168;    // f16 [1024][512]
static const size_t OFF_BIAS = 1183744;   // f32 [4][1024]
static const size_t OFF_FCW  = 1200128;   // f32 [512*64]
static const size_t OFF_WQ8  = 1331200;   // u32 [4][1024][64] int8 W_hh (1 MB)
static const size_t OFF_WIH0 = 3428352;   // u32 [2][1024][32]
static const size_t OFF_WIH1 = 3690496;   // u32 [2][1024][256]
static const size_t OFF_XQ   = 5787648;   // u32 [T][32]
static const size_t OFF_H0   = 9981952;   // f16 [T][512]
static const size_t OFF_XG   = 43536384;  // f16 xgT [ndir][1024][T], LAST
static const size_t XG_DIR   = (size_t)T_SEQ * 1024 * 2;  // 67108864 bytes
static const size_t NEED_PAR = OFF_XG + 2 * XG_DIR;       // 177754112

// ---------------- helpers ----------------
__device__ __forceinline__ float bf2f(u16 u) {
  union { u32 i; float f; } v; v.i = ((u32)u) << 16; return v.f;
}
__device__ __forceinline__ u16 f2bf(float f) {
  union { float f; u32 i; } v; v.f = f;
  u32 u = v.i;
  return (u16)((u + 0x7fffu + ((u >> 16) & 1u)) >> 16);
}
__device__ __forceinline__ u32 packf2(float a, float b) {
  f16x2 p; p.x = (f16)a; p.y = (f16)b;
  return __builtin_bit_cast(u32, p);
}
__device__ __forceinline__ u32 bf2f2(u32 v) {  // two bf16 -> two f16
  union { u32 i; float f; } lo, hi;
  lo.i = v << 16; hi.i = v & 0xffff0000u;
  return packf2(lo.f, hi.f);
}
__device__ __forceinline__ float ldf(const void* p, size_t i, u32 isf) {
  return isf ? ((const float*)p)[i] : bf2f(((const u16*)p)[i]);
}
__device__ __forceinline__ float fdot2f(f16x2 a, f16x2 b, float c) {
#if __has_builtin(__builtin_amdgcn_fdot2)
  return __builtin_amdgcn_fdot2(a, b, c, false);
#else
  return c + (float)a.x * (float)b.x + (float)a.y * (float)b.y;
#endif
}
__device__ __forceinline__ float fdotu(u32 a, u32 b, float c) {
  return fdot2f(__builtin_bit_cast(f16x2, a), __builtin_bit_cast(f16x2, b), c);
}
__device__ __forceinline__ int sdot4(u32 a, u32 b, int c) {
#if __has_builtin(__builtin_amdgcn_sdot4)
  return __builtin_amdgcn_sdot4((int)a, (int)b, c, false);
#else
  int r = c;
#pragma unroll
  for (int j = 0; j < 4; ++j)
    r += (int)(signed char)(a >> (8 * j)) * (int)(signed char)(b >> (8 * j));
  return r;
#endif
}
// lane permutes: DPP (VALU) + ds_swizzle (DS pipe) where DPP can't express.
__device__ __forceinline__ int dpp_xor1(int x) {  // quad_perm [1,0,3,2]
#if __has_builtin(__builtin_amdgcn_update_dpp)
  return __builtin_amdgcn_update_dpp(0, x, 0xB1, 0xF, 0xF, true);
#else
  return __shfl_xor(x, 1);
#endif
}
__device__ __forceinline__ int dpp_xor2(int x) {  // quad_perm [2,3,0,1]
#if __has_builtin(__builtin_amdgcn_update_dpp)
  return __builtin_amdgcn_update_dpp(0, x, 0x4E, 0xF, 0xF, true);
#else
  return __shfl_xor(x, 2);
#endif
}
__device__ __forceinline__ int dpp_ror8(int x) {  // row_ror:8 == xor8 in row16
#if __has_builtin(__builtin_amdgcn_update_dpp)
  return __builtin_amdgcn_update_dpp(0, x, 0x128, 0xF, 0xF, true);
#else
  return __shfl_xor(x, 8);
#endif
}
__device__ __forceinline__ int swz_xor4(int x) {  // lane ^ 4 (BitMode)
#if __has_builtin(__builtin_amdgcn_ds_swizzle)
  return __builtin_amdgcn_ds_swizzle(x, 0x101F);
#else
  return __shfl_xor(x, 4);
#endif
}
template <int CTRL>
__device__ __forceinline__ float dpp_bcastf(float x) {  // quad broadcast
#if __has_builtin(__builtin_amdgcn_update_dpp)
  return __builtin_bit_cast(float,
      __builtin_amdgcn_update_dpp(0, __builtin_bit_cast(int, x), CTRL, 0xF, 0xF, true));
#else
  return __shfl(x, (threadIdx.x & ~3) + (CTRL & 3));
#endif
}
__device__ __forceinline__ float tanhf_fast(float x) {
  return 1.0f - 2.0f * __builtin_amdgcn_rcpf(1.0f + __builtin_amdgcn_exp2f(2.8853900817779268f * x));
}
// raw workgroup barrier WITHOUT the vmcnt(0) drain __syncthreads imposes:
// only LDS (lgkmcnt) ordering is needed for the h-byte exchange; global
// loads/stores stay in flight across the barrier.
__device__ __forceinline__ void wg_barrier_lds() {
  asm volatile("s_waitcnt lgkmcnt(0)" ::: "memory");
  __builtin_amdgcn_s_barrier();
  asm volatile("" ::: "memory");
}

// ---------------- dtype detection ----------------
__global__ void k_detect(const u16* __restrict__ probe, u32* __restrict__ dt) {
  __shared__ int cnt;
  if (threadIdx.x == 0) cnt = 0;
  __syncthreads();
  int bad = 0;
  for (int i = threadIdx.x; i < 8192; i += 256) {
    float v = bf2f(probe[i]);
    if (!(v * v <= 16.0f)) bad++;
  }
  atomicAdd(&cnt, bad);
  __syncthreads();
  if (threadIdx.x == 0) *dt = (cnt > 64) ? 1u : 0u;
}

// ---------------- conversions ----------------
__global__ void k_conv_pairs(const void* __restrict__ src, u32* __restrict__ dst,
                             int np, const u32* __restrict__ dtp) {
  u32 isf = *dtp;
  int i = blockIdx.x * 256 + threadIdx.x;
  if (i >= np) return;
  if (isf) {
    const float* s = (const float*)src;
    dst[i] = packf2(s[2 * i], s[2 * i + 1]);
  } else {
    dst[i] = bf2f2(((const u32*)src)[i]);
  }
}

// int8-quantize one W_hh matrix [1024][256] -> u32 [1024][64], scale 2048
__global__ void k_quant(const void* __restrict__ src, u32* __restrict__ dst,
                        const u32* __restrict__ dtp) {
  u32 isf = *dtp;
  int i = blockIdx.x * 256 + threadIdx.x;  // 65536
  int row = i >> 6, c = i & 63;
  u32 out = 0;
#pragma unroll
  for (int j = 0; j < 4; ++j) {
    float w = ldf(src, (size_t)row * 256 + 4 * c + j, isf);
    int q = (int)rintf(w * 2048.0f);
    q = q > 127 ? 127 : (q < -127 ? -127 : q);
    out |= ((u32)(q & 0xff)) << (8 * j);
  }
  dst[i] = out;
}

__global__ void k_conv_misc(const void* bi0f, const void* bh0f, const void* bi0b, const void* bh0b,
                            const void* bi1f, const void* bh1f, const void* bi1b, const void* bh1b,
                            const void* fcb, float* __restrict__ bias, float* __restrict__ fcw,
                            u32* __restrict__ flags, int* __restrict__ map,
                            const u32* __restrict__ dtp) {
  u32 isf = *dtp;
  int i = blockIdx.x * 256 + threadIdx.x;
  if (i < 4096) {
    int ld = i >> 10, r = i & 1023;
    const void* bi; const void* bh;
    if (ld == 0)      { bi = bi0f; bh = bh0f; }
    else if (ld == 1) { bi = bi0b; bh = bh0b; }
    else if (ld == 2) { bi = bi1f; bh = bh1f; }
    else              { bi = bi1b; bh = bh1b; }
    bias[i] = ldf(bi, r, isf) + ldf(bh, r, isf);
  } else if (i < 36864) {
    fcw[i - 4096] = ldf(fcb, i - 4096, isf);
  } else if (i < 36992) {
    flags[i - 36864] = 0;
  } else if (i < 69760) {
    map[i - 36992] = -1;
  }
}

__global__ void k_conv_x(const void* __restrict__ Y, const void* __restrict__ dT,
                         u32* __restrict__ xq, const u32* __restrict__ dtp) {
  u32 isf = *dtp;
  int i = blockIdx.x * 256 + threadIdx.x;  // T*32
  if (i >= T_SEQ * 32) return;
  int t = i >> 5, m = i & 31, k2 = 2 * m;
  float a = ldf(Y, (size_t)t * 63 + k2, isf);
  float b = (k2 + 1 < 63) ? ldf(Y, (size_t)t * 63 + k2 + 1, isf) : ldf(dT, t, isf);
  xq[i] = packf2(a, b);
}

__global__ void k_map_set(const int* __restrict__ idx, int* __restrict__ map) {
  int i = blockIdx.x * 256 + threadIdx.x;
  if (i < 1024) map[idx[i]] = i;
}

// ---------------- input-projection GEMM ----------------
// Writes xg TRANSPOSED: xgT[row r][time t], with t-REVERSED storage when
// rev=1 so the recurrence always streams ascending addresses.
__global__ __launch_bounds__(256) void k_gemm(
    const u32* __restrict__ Aq, const u32* __restrict__ Wc,
    const float* __restrict__ bias, f16* __restrict__ xgT, int Kp, int rev) {
  int t0 = blockIdx.x << 6, r0 = blockIdx.y << 6;
  int tid = threadIdx.x, tx = tid & 15, ty = tid >> 4;
  __shared__ u32 As[64][33];
  __shared__ u32 Bs[64][33];
  float acc[4][4] = {};
  for (int kp0 = 0; kp0 < Kp; kp0 += 32) {
#pragma unroll
    for (int i = 0; i < 8; ++i) {
      int idx = tid + (i << 8);
      int row = idx >> 5, kp = idx & 31, kpg = kp0 + kp;
      As[row][kp] = Aq[(size_t)(t0 + row) * Kp + kpg];
      Bs[row][kp] = Wc[(size_t)(r0 + row) * Kp + kpg];
    }
    __syncthreads();
#pragma unroll 4
    for (int kk = 0; kk < 32; ++kk) {
      u32 av[4], bv[4];
#pragma unroll
      for (int i = 0; i < 4; ++i) av[i] = As[ty * 4 + i][kk];
#pragma unroll
      for (int i = 0; i < 4; ++i) bv[i] = Bs[tx * 4 + i][kk];
#pragma unroll
      for (int i = 0; i < 4; ++i)
#pragma unroll
        for (int j = 0; j < 4; ++j)
          acc[i][j] = fdotu(av[i], bv[j], acc[i][j]);
    }
    __syncthreads();
  }
  int tb = t0 + (ty << 2);
#pragma unroll
  for (int j = 0; j < 4; ++j) {
    int rr = r0 + tx * 4 + j;
    float b = bias[rr];
    f16 v0 = (f16)(acc[0][j] + b);
    f16 v1 = (f16)(acc[1][j] + b);
    f16 v2 = (f16)(acc[2][j] + b);
    f16 v3 = (f16)(acc[3][j] + b);
    size_t base = (size_t)rr * T_SEQ;
    f16x4 v;
    size_t pos;
    if (rev) { pos = base + (size_t)(T_SEQ - 4 - tb); v = (f16x4){v3, v2, v1, v0}; }
    else     { pos = base + (size_t)tb;               v = (f16x4){v0, v1, v2, v3}; }
    *(f16x4*)(xgT + pos) = v;
  }
}

// ---------------- recurrence v5 ------------------------------------------
// 1024 threads, 16-way K-split with XOR-permuted row assignment.
// Thread = (group g16 = tid>>4, lane s = tid&15). Thread owns K-chunk
// [16s,16s+16) of 16 rows: slot t holds row (t^s) of its group's 4 units
// (row r: unit g16*4 + (r>>2), gate r&3). Properties:
//  - h read: ONE ds_read_b128 per thread (16/CU/step, was 64; LDS pipe was
//    ~640 cyc/step of broadcast re-reads at step start — the round-4
//    bottleneck after the AGPR-copy theory died).
//  - zero-select butterfly: because slot t of lane s and slot t^d of lane
//    s^d hold the SAME row, the reduce is plain adds: no cndmasks.
//    xor1/xor2 via DPP quad-perm, xor4 via ds_swizzle, xor8 via row_ror:8.
//  - after the butterfly lane s holds gate (s&3) of unit g16*4+(s>>2):
//    activation is fully non-redundant; quad-broadcast rebuilds the 4
//    gates per unit exactly as before (math bit-identical).
template <bool HASMAP>
__global__ __launch_bounds__(1024)
__attribute__((amdgpu_waves_per_eu(4, 4))) void k_recur2(
    const f16* __restrict__ xgT, const u32* __restrict__ wq,
    f16* __restrict__ h_full, f16* __restrict__ h1g,
    const int* __restrict__ map, int dir0) {
  const int dir = dir0 + blockIdx.x;
  const int tid = threadIdx.x;
  const int g16 = tid >> 4;
  const int s = tid & 15;
  const int u = (g16 << 2) + (s >> 2);  // unit this lane's final row maps to
  const u32* wqd = wq + ((size_t)dir << 16);  // [1024][64]

  __shared__ __align__(16) unsigned char hb8[2][256];  // double-buffered h (i8)

  // weights: slot t -> row (t^s), K-dwords [4s,4s+4)
  uint4 w[16];
  {
    const uint4* pw = (const uint4*)wqd;  // row stride = 16 uint4
#pragma unroll
    for (int t = 0; t < 16; ++t) {
      int r = t ^ s;
      w[t] = pw[(size_t)((((r & 3) << 8) + (g16 << 2) + (r >> 2)) * 16 + s)];
    }
  }

  if (tid < 128) ((u32*)hb8)[tid] = 0;

  const float ksc = 1.0f / (2048.0f * 127.0f);
  // per-lane activation params: sigmoid for gates i,f,o; tanh for gate g(=2)
  const float sk = ((s & 3) == 2) ? 2.8853900817779268f : -1.4426950408889634f;
  const float aa = ((s & 3) == 2) ? -2.0f : 1.0f;
  const float bb = ((s & 3) == 2) ? 1.0f : 0.0f;

  const f16* xg_d = xgT + (size_t)blockIdx.x * ((size_t)T_SEQ * 1024);
  const f16* xrow = xg_d + (size_t)(((s & 3) << 8) | u) * T_SEQ;  // own gate row

  const int tstep = dir ? -1 : 1;
  int t = dir ? (T_SEQ - 1) : 0;
  int mp = HASMAP ? map[t] : -1;
  float c_state = 0.f;

  // incremental h-output pointer (valid only when h_full != null)
  f16* hout = h_full ? (h_full + (size_t)t * 512 + (dir << 8) + u) : nullptr;
  const ptrdiff_t hstride = (ptrdiff_t)tstep * 512;

  uint4 xcur = *(const uint4*)xrow;  // steps 0..7 of own gate
  uint4 xnxt = xcur;

  __syncthreads();  // hb8 zero visible (full drain once, outside the loop)

  for (int ch = 0; ch < T_SEQ / 8; ++ch) {
    if (ch + 1 < T_SEQ / 8) xnxt = *(const uint4*)(xrow + (((size_t)ch + 1) << 3));
#pragma unroll
    for (int j = 0; j < 8; ++j) {
      // own-gate pre-activation input for this step (static extract)
      u32 dw = (j >> 1) == 0 ? xcur.x : (j >> 1) == 1 ? xcur.y
             : (j >> 1) == 2 ? xcur.z : xcur.w;
      f16x2 pr = __builtin_bit_cast(f16x2, dw);
      float xb = (float)((j & 1) ? pr.y : pr.x);

      int ms = mp;
      if (HASMAP) {  // seq-mode only: prefetch next map slot
        int tn = t + tstep;
        int idx2 = ((unsigned)tn < T_SEQ) ? tn : t;
        mp = map[idx2];
      }

      // ONE b128: this lane's 16 h-bytes (K [16s,16s+16))
      uint4 hv = ((const uint4*)hb8)[((j & 1) << 4) + s];

      int a0, a1, a2, a3, a4, a5, a6, a7, a8, a9, a10, a11, a12, a13, a14, a15;
#define DOTSLOT(A, T)                                             \
      A = sdot4(w[T].w, hv.w,                                     \
          sdot4(w[T].z, hv.z,                                     \
          sdot4(w[T].y, hv.y,                                     \
          sdot4(w[T].x, hv.x, 0))));
      DOTSLOT(a0, 0)   DOTSLOT(a1, 1)   DOTSLOT(a2, 2)   DOTSLOT(a3, 3)
      DOTSLOT(a4, 4)   DOTSLOT(a5, 5)   DOTSLOT(a6, 6)   DOTSLOT(a7, 7)
      DOTSLOT(a8, 8)   DOTSLOT(a9, 9)   DOTSLOT(a10, 10) DOTSLOT(a11, 11)
      DOTSLOT(a12, 12) DOTSLOT(a13, 13) DOTSLOT(a14, 14) DOTSLOT(a15, 15)
#undef DOTSLOT
      // zero-select butterfly (exact integer adds, bit-identical result):
      // B[j']=A[2j']+xor1(A[2j'+1]) pairs identical rows, etc.
      int b0 = a0 + dpp_xor1(a1);
      int b1 = a2 + dpp_xor1(a3);
      int b2 = a4 + dpp_xor1(a5);
      int b3 = a6 + dpp_xor1(a7);
      int b4 = a8 + dpp_xor1(a9);
      int b5 = a10 + dpp_xor1(a11);
      int b6 = a12 + dpp_xor1(a13);
      int b7 = a14 + dpp_xor1(a15);
      int c0 = b0 + dpp_xor2(b1);
      int c1 = b2 + dpp_xor2(b3);
      int c2 = b4 + dpp_xor2(b5);
      int c3 = b6 + dpp_xor2(b7);
      int d0 = c0 + swz_xor4(c1);
      int d1 = c2 + swz_xor4(c3);
      int e  = d0 + dpp_ror8(d1);  // lane s: full-K sum of row s

      float x = __builtin_fmaf((float)e, ksc, xb);
      float r = __builtin_amdgcn_rcpf(1.0f + __builtin_amdgcn_exp2f(sk * x));
      float g = __builtin_fmaf(aa, r, bb);  // own activated gate
      float gi = dpp_bcastf<0x00>(g);
      float gf = dpp_bcastf<0x55>(g);
      float gg = dpp_bcastf<0xAA>(g);
      float go = dpp_bcastf<0xFF>(g);
      c_state = __builtin_fmaf(gf, c_state, gi * gg);
      float h = go * tanhf_fast(c_state);
      int q8 = (int)rintf(h * 127.0f);
      if ((s & 3) == 0) {
        hb8[(j & 1) ^ 1][u] = (unsigned char)(q8 & 0xff);
        if (h_full) *hout = (f16)h;
        if (HASMAP && ms >= 0) h1g[(size_t)ms * 512 + (dir << 8) + u] = (f16)h;
      }
      wg_barrier_lds();  // LDS-only wait; global ops stay in flight
      t += tstep;
      hout += hstride;
    }
    xcur = xnxt;
  }
}

// ---------------- FC + gather ----------------
// mapn == null: slot = idx[n] (dense h layout); else slot = mapn[idx[n]].
__global__ void k_fc(const f16* __restrict__ hbase, const int* __restrict__ mapn,
                     const int* __restrict__ idx, const float* __restrict__ fcw,
                     void* __restrict__ out, const u32* __restrict__ dtp) {
  u32 isf = *dtp;
  int n = blockIdx.x;
  int cc = threadIdx.x;  // 64
  int slot = mapn ? mapn[idx[n]] : idx[n];
  const f16* hp = hbase + (size_t)slot * 512;
  float acc = 0.f;
#pragma unroll 8
  for (int k = 0; k < 512; ++k) acc += (float)hp[k] * fcw[k * 64 + cc];
  int o = (cc < 32) ? (n * 32 + cc) : (32 * 1024 + n * 32 + (cc - 32));
  if (isf) ((float*)out)[o] = acc;
  else     ((u16*)out)[o]   = f2bf(acc);
}

// ---------------- launch ----------------
extern "C" void kernel_launch(void* const* d_in, const int* in_sizes, int n_in,
                              void* d_out, int out_size, void* d_ws, size_t ws_size,
                              hipStream_t stream) {
  const void* Y        = d_in[0];
  const void* dT       = d_in[1];
  const int*  idx      = (const int*)d_in[2];
  const void* w_ih_l0f = d_in[3];
  const void* w_hh_l0f = d_in[4];
  const void* b_ih_l0f = d_in[5];
  const void* b_hh_l0f = d_in[6];
  const void* w_ih_l0b = d_in[7];
  const void* w_hh_l0b = d_in[8];
  const void* b_ih_l0b = d_in[9];
  const void* b_hh_l0b = d_in[10];
  const void* w_ih_l1f = d_in[11];
  const void* w_hh_l1f = d_in[12];
  const void* b_ih_l1f = d_in[13];
  const void* b_hh_l1f = d_in[14];
  const void* w_ih_l1b = d_in[15];
  const void* w_hh_l1b = d_in[16];
  const void* b_ih_l1b = d_in[17];
  const void* b_hh_l1b = d_in[18];
  const void* fcbf     = d_in[19];

  char* ws = (char*)d_ws;
  u32*  dt    = (u32*)(ws + OFF_DT);
  u32*  flags = (u32*)(ws + OFF_FLG);
  int*  map   = (int*)(ws + OFF_MAP);
  f16*  h1g   = (f16*)(ws + OFF_H1G);
  float* bias = (float*)(ws + OFF_BIAS);
  float* fcw  = (float*)(ws + OFF_FCW);
  u32*  wq8   = (u32*)(ws + OFF_WQ8);
  u32*  wih0  = (u32*)(ws + OFF_WIH0);
  u32*  wih1  = (u32*)(ws + OFF_WIH1);
  u32*  xq    = (u32*)(ws + OFF_XQ);
  f16*  h0    = (f16*)(ws + OFF_H0);
  f16*  xg    = (f16*)(ws + OFF_XG);
  f16*  xg1   = xg + XG_DIR / 2;  // f16 elements

  const int par = (ws_size >= NEED_PAR) ? 1 : 0;

  k_detect<<<1, 256, 0, stream>>>((const u16*)w_hh_l0f, dt);
  k_quant<<<256, 256, 0, stream>>>(w_hh_l0f, wq8 + 0 * 65536, dt);
  k_quant<<<256, 256, 0, stream>>>(w_hh_l0b, wq8 + 1 * 65536, dt);
  k_quant<<<256, 256, 0, stream>>>(w_hh_l1f, wq8 + 2 * 65536, dt);
  k_quant<<<256, 256, 0, stream>>>(w_hh_l1b, wq8 + 3 * 65536, dt);
  k_conv_pairs<<<128, 256, 0, stream>>>(w_ih_l0f, wih0 + 0, 32768, dt);
  k_conv_pairs<<<128, 256, 0, stream>>>(w_ih_l0b, wih0 + 32768, 32768, dt);
  k_conv_pairs<<<1024, 256, 0, stream>>>(w_ih_l1f, wih1 + 0, 262144, dt);
  k_conv_pairs<<<1024, 256, 0, stream>>>(w_ih_l1b, wih1 + 262144, 262144, dt);
  k_conv_misc<<<273, 256, 0, stream>>>(b_ih_l0f, b_hh_l0f, b_ih_l0b, b_hh_l0b,
                                       b_ih_l1f, b_hh_l1f, b_ih_l1b, b_hh_l1b,
                                       fcbf, bias, fcw, flags, map, dt);
  k_conv_x<<<4096, 256, 0, stream>>>(Y, dT, xq, dt);
  k_map_set<<<4, 256, 0, stream>>>(idx, map);

  dim3 ggrid(T_SEQ / 64, 16);
  if (par) {
    k_gemm<<<ggrid, 256, 0, stream>>>(xq, wih0, bias, xg, 32, 0);
    k_gemm<<<ggrid, 256, 0, stream>>>(xq, wih0 + 32768, bias + 1024, xg1, 32, 1);
    k_recur2<false><<<2, 1024, 0, stream>>>(xg, wq8, h0, nullptr, nullptr, 0);
    k_gemm<<<ggrid, 256, 0, stream>>>((const u32*)h0, wih1, bias + 2048, xg, 256, 0);
    k_gemm<<<ggrid, 256, 0, stream>>>((const u32*)h0, wih1 + 262144, bias + 3072, xg1, 256, 1);
    // L1 writes dense h into h0 (free after the two gemms above); no map.
    k_recur2<false><<<2, 1024, 0, stream>>>(xg, wq8 + 2 * 65536, h0, nullptr, nullptr, 0);
    k_fc<<<1024, 64, 0, stream>>>(h0, nullptr, idx, fcw, d_out, dt);
  } else {
    k_gemm<<<ggrid, 256, 0, stream>>>(xq, wih0, bias, xg, 32, 0);
    k_recur2<false><<<1, 1024, 0, stream>>>(xg, wq8, h0, nullptr, nullptr, 0);
    k_gemm<<<ggrid, 256, 0, stream>>>(xq, wih0 + 32768, bias + 1024, xg, 32, 1);
    k_recur2<false><<<1, 1024, 0, stream>>>(xg, wq8, h0, nullptr, nullptr, 1);
    k_gemm<<<ggrid, 256, 0, stream>>>((const u32*)h0, wih1, bias + 2048, xg, 256, 0);
    k_recur2<true><<<1, 1024, 0, stream>>>(xg, wq8 + 2 * 65536, nullptr, h1g, map, 0);
    k_gemm<<<ggrid, 256, 0, stream>>>((const u32*)h0, wih1 + 262144, bias + 3072, xg, 256, 1);
    k_recur2<true><<<1, 1024, 0, stream>>>(xg, wq8 + 2 * 65536, nullptr, h1g, map, 1);
    k_fc<<<1024, 64, 0, stream>>>(h1g, map, idx, fcw, d_out, dt);
  }
}

// Round 6
// 61074.249 us; speedup vs baseline: 1.0085x; 1.0085x over previous
//
#include <hip/hip_runtime.h>

typedef unsigned int u32;
typedef unsigned short u16;
typedef _Float16 f16;
typedef _Float16 f16x2 __attribute__((ext_vector_type(2)));
typedef _Float16 f16x4 __attribute__((ext_vector_type(4)));

#define T_SEQ 32768

// ---------------- ws layout (bytes) ----------------
static const size_t OFF_DT   = 0;         // u32 dtype flag (1 = f32 inputs)
static const size_t OFF_FLG  = 1024;      // u32[128] (legacy, kept zeroed)
static const size_t OFF_MAP  = 4096;      // int [T]
static const size_t OFF_H1G  = 135168;    // f16 [1024][512]
static const size_t OFF_BIAS = 1183744;   // f32 [4][1024]
static const size_t OFF_FCW  = 1200128;   // f32 [512*64]
static const size_t OFF_WQ8  = 1331200;   // u32 [4][1024][64] int8 W_hh (1 MB)
static const size_t OFF_WIH0 = 3428352;   // u32 [2][1024][32]
static const size_t OFF_WIH1 = 3690496;   // u32 [2][1024][256]
static const size_t OFF_XQ   = 5787648;   // u32 [T][32]
static const size_t OFF_H0   = 9981952;   // f16 [T][512]
static const size_t OFF_XG   = 43536384;  // f16 xgT [ndir][1024][T], LAST
static const size_t XG_DIR   = (size_t)T_SEQ * 1024 * 2;  // 67108864 bytes
static const size_t NEED_PAR = OFF_XG + 2 * XG_DIR;       // 177754112

// ---------------- helpers ----------------
__device__ __forceinline__ float bf2f(u16 u) {
  union { u32 i; float f; } v; v.i = ((u32)u) << 16; return v.f;
}
__device__ __forceinline__ u16 f2bf(float f) {
  union { float f; u32 i; } v; v.f = f;
  u32 u = v.i;
  return (u16)((u + 0x7fffu + ((u >> 16) & 1u)) >> 16);
}
__device__ __forceinline__ u32 packf2(float a, float b) {
  f16x2 p; p.x = (f16)a; p.y = (f16)b;
  return __builtin_bit_cast(u32, p);
}
__device__ __forceinline__ u32 bf2f2(u32 v) {  // two bf16 -> two f16
  union { u32 i; float f; } lo, hi;
  lo.i = v << 16; hi.i = v & 0xffff0000u;
  return packf2(lo.f, hi.f);
}
__device__ __forceinline__ float ldf(const void* p, size_t i, u32 isf) {
  return isf ? ((const float*)p)[i] : bf2f(((const u16*)p)[i]);
}
__device__ __forceinline__ float fdot2f(f16x2 a, f16x2 b, float c) {
#if __has_builtin(__builtin_amdgcn_fdot2)
  return __builtin_amdgcn_fdot2(a, b, c, false);
#else
  return c + (float)a.x * (float)b.x + (float)a.y * (float)b.y;
#endif
}
__device__ __forceinline__ float fdotu(u32 a, u32 b, float c) {
  return fdot2f(__builtin_bit_cast(f16x2, a), __builtin_bit_cast(f16x2, b), c);
}
__device__ __forceinline__ int sdot4(u32 a, u32 b, int c) {
#if __has_builtin(__builtin_amdgcn_sdot4)
  return __builtin_amdgcn_sdot4((int)a, (int)b, c, false);
#else
  int r = c;
#pragma unroll
  for (int j = 0; j < 4; ++j)
    r += (int)(signed char)(a >> (8 * j)) * (int)(signed char)(b >> (8 * j));
  return r;
#endif
}
// lane permutes: all VALU DPP (no LDS pipe in the per-step chain).
__device__ __forceinline__ int dpp_xor1(int x) {  // quad_perm [1,0,3,2]
#if __has_builtin(__builtin_amdgcn_update_dpp)
  return __builtin_amdgcn_update_dpp(0, x, 0xB1, 0xF, 0xF, true);
#else
  return __shfl_xor(x, 1);
#endif
}
__device__ __forceinline__ int dpp_xor2(int x) {  // quad_perm [2,3,0,1]
#if __has_builtin(__builtin_amdgcn_update_dpp)
  return __builtin_amdgcn_update_dpp(0, x, 0x4E, 0xF, 0xF, true);
#else
  return __shfl_xor(x, 2);
#endif
}
__device__ __forceinline__ int dpp_ror8(int x) {  // row_ror:8 == lane^8 in row16
#if __has_builtin(__builtin_amdgcn_update_dpp)
  return __builtin_amdgcn_update_dpp(0, x, 0x128, 0xF, 0xF, true);
#else
  return __shfl_xor(x, 8);
#endif
}
template <int CTRL>
__device__ __forceinline__ float dpp_bcastf(float x) {  // quad broadcast
#if __has_builtin(__builtin_amdgcn_update_dpp)
  return __builtin_bit_cast(float,
      __builtin_amdgcn_update_dpp(0, __builtin_bit_cast(int, x), CTRL, 0xF, 0xF, true));
#else
  return __shfl(x, (threadIdx.x & ~3) + (CTRL & 3));
#endif
}
__device__ __forceinline__ float tanhf_fast(float x) {
  return 1.0f - 2.0f * __builtin_amdgcn_rcpf(1.0f + __builtin_amdgcn_exp2f(2.8853900817779268f * x));
}
// raw workgroup barrier WITHOUT the vmcnt(0) drain __syncthreads imposes:
// only LDS (lgkmcnt) ordering is needed for the h-byte exchange; global
// loads/stores stay in flight across the barrier.
__device__ __forceinline__ void wg_barrier_lds() {
  asm volatile("s_waitcnt lgkmcnt(0)" ::: "memory");
  __builtin_amdgcn_s_barrier();
  asm volatile("" ::: "memory");
}

// ---------------- dtype detection ----------------
__global__ void k_detect(const u16* __restrict__ probe, u32* __restrict__ dt) {
  __shared__ int cnt;
  if (threadIdx.x == 0) cnt = 0;
  __syncthreads();
  int bad = 0;
  for (int i = threadIdx.x; i < 8192; i += 256) {
    float v = bf2f(probe[i]);
    if (!(v * v <= 16.0f)) bad++;
  }
  atomicAdd(&cnt, bad);
  __syncthreads();
  if (threadIdx.x == 0) *dt = (cnt > 64) ? 1u : 0u;
}

// ---------------- conversions ----------------
__global__ void k_conv_pairs(const void* __restrict__ src, u32* __restrict__ dst,
                             int np, const u32* __restrict__ dtp) {
  u32 isf = *dtp;
  int i = blockIdx.x * 256 + threadIdx.x;
  if (i >= np) return;
  if (isf) {
    const float* s = (const float*)src;
    dst[i] = packf2(s[2 * i], s[2 * i + 1]);
  } else {
    dst[i] = bf2f2(((const u32*)src)[i]);
  }
}

// int8-quantize one W_hh matrix [1024][256] -> u32 [1024][64], scale 2048
__global__ void k_quant(const void* __restrict__ src, u32* __restrict__ dst,
                        const u32* __restrict__ dtp) {
  u32 isf = *dtp;
  int i = blockIdx.x * 256 + threadIdx.x;  // 65536
  int row = i >> 6, c = i & 63;
  u32 out = 0;
#pragma unroll
  for (int j = 0; j < 4; ++j) {
    float w = ldf(src, (size_t)row * 256 + 4 * c + j, isf);
    int q = (int)rintf(w * 2048.0f);
    q = q > 127 ? 127 : (q < -127 ? -127 : q);
    out |= ((u32)(q & 0xff)) << (8 * j);
  }
  dst[i] = out;
}

__global__ void k_conv_misc(const void* bi0f, const void* bh0f, const void* bi0b, const void* bh0b,
                            const void* bi1f, const void* bh1f, const void* bi1b, const void* bh1b,
                            const void* fcb, float* __restrict__ bias, float* __restrict__ fcw,
                            u32* __restrict__ flags, int* __restrict__ map,
                            const u32* __restrict__ dtp) {
  u32 isf = *dtp;
  int i = blockIdx.x * 256 + threadIdx.x;
  if (i < 4096) {
    int ld = i >> 10, r = i & 1023;
    const void* bi; const void* bh;
    if (ld == 0)      { bi = bi0f; bh = bh0f; }
    else if (ld == 1) { bi = bi0b; bh = bh0b; }
    else if (ld == 2) { bi = bi1f; bh = bh1f; }
    else              { bi = bi1b; bh = bh1b; }
    bias[i] = ldf(bi, r, isf) + ldf(bh, r, isf);
  } else if (i < 36864) {
    fcw[i - 4096] = ldf(fcb, i - 4096, isf);
  } else if (i < 36992) {
    flags[i - 36864] = 0;
  } else if (i < 69760) {
    map[i - 36992] = -1;
  }
}

__global__ void k_conv_x(const void* __restrict__ Y, const void* __restrict__ dT,
                         u32* __restrict__ xq, const u32* __restrict__ dtp) {
  u32 isf = *dtp;
  int i = blockIdx.x * 256 + threadIdx.x;  // T*32
  if (i >= T_SEQ * 32) return;
  int t = i >> 5, m = i & 31, k2 = 2 * m;
  float a = ldf(Y, (size_t)t * 63 + k2, isf);
  float b = (k2 + 1 < 63) ? ldf(Y, (size_t)t * 63 + k2 + 1, isf) : ldf(dT, t, isf);
  xq[i] = packf2(a, b);
}

__global__ void k_map_set(const int* __restrict__ idx, int* __restrict__ map) {
  int i = blockIdx.x * 256 + threadIdx.x;
  if (i < 1024) map[idx[i]] = i;
}

// ---------------- input-projection GEMM ----------------
// Writes xg TRANSPOSED: xgT[row r][time t], with t-REVERSED storage when
// rev=1 so the recurrence always streams ascending addresses.
__global__ __launch_bounds__(256) void k_gemm(
    const u32* __restrict__ Aq, const u32* __restrict__ Wc,
    const float* __restrict__ bias, f16* __restrict__ xgT, int Kp, int rev) {
  int t0 = blockIdx.x << 6, r0 = blockIdx.y << 6;
  int tid = threadIdx.x, tx = tid & 15, ty = tid >> 4;
  __shared__ u32 As[64][33];
  __shared__ u32 Bs[64][33];
  float acc[4][4] = {};
  for (int kp0 = 0; kp0 < Kp; kp0 += 32) {
#pragma unroll
    for (int i = 0; i < 8; ++i) {
      int idx = tid + (i << 8);
      int row = idx >> 5, kp = idx & 31, kpg = kp0 + kp;
      As[row][kp] = Aq[(size_t)(t0 + row) * Kp + kpg];
      Bs[row][kp] = Wc[(size_t)(r0 + row) * Kp + kpg];
    }
    __syncthreads();
#pragma unroll 4
    for (int kk = 0; kk < 32; ++kk) {
      u32 av[4], bv[4];
#pragma unroll
      for (int i = 0; i < 4; ++i) av[i] = As[ty * 4 + i][kk];
#pragma unroll
      for (int i = 0; i < 4; ++i) bv[i] = Bs[tx * 4 + i][kk];
#pragma unroll
      for (int i = 0; i < 4; ++i)
#pragma unroll
        for (int j = 0; j < 4; ++j)
          acc[i][j] = fdotu(av[i], bv[j], acc[i][j]);
    }
    __syncthreads();
  }
  int tb = t0 + (ty << 2);
#pragma unroll
  for (int j = 0; j < 4; ++j) {
    int rr = r0 + tx * 4 + j;
    float b = bias[rr];
    f16 v0 = (f16)(acc[0][j] + b);
    f16 v1 = (f16)(acc[1][j] + b);
    f16 v2 = (f16)(acc[2][j] + b);
    f16 v3 = (f16)(acc[3][j] + b);
    size_t base = (size_t)rr * T_SEQ;
    f16x4 v;
    size_t pos;
    if (rev) { pos = base + (size_t)(T_SEQ - 4 - tb); v = (f16x4){v3, v2, v1, v0}; }
    else     { pos = base + (size_t)tb;               v = (f16x4){v0, v1, v2, v3}; }
    *(f16x4*)(xgT + pos) = v;
  }
}

// ---------------- recurrence v6 ------------------------------------------
// 1024 threads, 8-way K-split, ALL-DPP butterfly (no ds_swizzle, no cndmask).
// Lane l in its wave: s = (l&3)|((l>>1)&4) indexes an 8-lane XOR group whose
// members are lanes with bit2 of l FIXED -> group XOR distances are
// {1,2,8} in lane space = {xor1 quad_perm, xor2 quad_perm, row_ror:8}, all
// VALU DPP. Slot t holds row (t^s) of the group's 8 rows (2 units x 4
// gates) over K-chunk s (8 dwords). After the 3-stage butterfly lane l
// holds the full-K sum of row s = gate (s&3) of unit ubase+(s>>2), and each
// QUAD holds gates 0-3 of one unit -> quad-broadcast works unchanged.
// vs R3 (best, 56.9k): -6 cndmask, half the h-read (2xb128=32B), sk folded
// into the reduce constant (xbs=sk*xb off-chain). vs R5: the 2 ds_swizzle
// LDS-pipe ops are OUT of the per-step dependency chain.
template <bool HASMAP>
__global__ __launch_bounds__(1024, 4) void k_recur2(
    const f16* __restrict__ xgT, const u32* __restrict__ wq,
    f16* __restrict__ h_full, f16* __restrict__ h1g,
    const int* __restrict__ map, int dir0) {
  const int dir = dir0 + blockIdx.x;
  const int tid = threadIdx.x;
  const int l = tid & 63, wv = tid >> 6;
  const int r16 = l >> 4, gbit = (l >> 2) & 1;
  const int s = (l & 3) | ((l >> 1) & 4);          // position in 8-lane group
  const int ubase = (wv << 4) + (r16 << 2) + (gbit << 1);
  const int u_own = ubase + (s >> 2);              // unit of this lane's row
  const u32* wqd = wq + ((size_t)dir << 16);       // [1024][64]

  __shared__ __align__(16) unsigned char hb8[2][256];  // double-buffered h (i8)

  // weights: slot t -> row (t^s) (gate (t^s)&3, unit ubase+((t^s)>>2)),
  // K-dwords [8s, 8s+8) as two uint4s.
  uint4 w[16];
  {
    const uint4* pw = (const uint4*)wqd;  // row stride = 16 uint4
#pragma unroll
    for (int t = 0; t < 8; ++t) {
      int rho = t ^ s;
      int R = ((rho & 3) << 8) | (ubase + (rho >> 2));
      w[2 * t]     = pw[(size_t)R * 16 + 2 * s];
      w[2 * t + 1] = pw[(size_t)R * 16 + 2 * s + 1];
    }
  }

  if (tid < 128) ((u32*)hb8)[tid] = 0;

  const float ksc = 1.0f / (2048.0f * 127.0f);
  // per-lane activation params: sigmoid for gates i,f,o; tanh for gate g(=2)
  const float sk = ((s & 3) == 2) ? 2.8853900817779268f : -1.4426950408889634f;
  const float aa = ((s & 3) == 2) ? -2.0f : 1.0f;
  const float bb = ((s & 3) == 2) ? 1.0f : 0.0f;
  const float kk = sk * ksc;  // fold the activation scale into the dot scale

  const f16* xg_d = xgT + (size_t)blockIdx.x * ((size_t)T_SEQ * 1024);
  const f16* xrow = xg_d + (size_t)(((s & 3) << 8) | u_own) * T_SEQ;  // own row

  const int tstep = dir ? -1 : 1;
  int t = dir ? (T_SEQ - 1) : 0;
  int mp = HASMAP ? map[t] : -1;
  float c_state = 0.f;

  // incremental h-output pointer (valid only when h_full != null)
  f16* hout = h_full ? (h_full + (size_t)t * 512 + (dir << 8) + u_own) : nullptr;
  const ptrdiff_t hstride = (ptrdiff_t)tstep * 512;

  uint4 xcur = *(const uint4*)xrow;  // steps 0..7 of own gate
  uint4 xnxt = xcur;

  __syncthreads();  // hb8 zero visible (full drain once, outside the loop)

  for (int ch = 0; ch < T_SEQ / 8; ++ch) {
    if (ch + 1 < T_SEQ / 8) xnxt = *(const uint4*)(xrow + (((size_t)ch + 1) << 3));
#pragma unroll
    for (int j = 0; j < 8; ++j) {
      // own-gate pre-activation input (static extract, off the chain)
      u32 dw = (j >> 1) == 0 ? xcur.x : (j >> 1) == 1 ? xcur.y
             : (j >> 1) == 2 ? xcur.z : xcur.w;
      f16x2 pr = __builtin_bit_cast(f16x2, dw);
      float xbs = sk * (float)((j & 1) ? pr.y : pr.x);

      int ms = mp;
      if (HASMAP) {  // seq-mode only: prefetch next map slot
        int tn = t + tstep;
        int idx2 = ((unsigned)tn < T_SEQ) ? tn : t;
        mp = map[idx2];
      }

      // this lane's 32 h-bytes (K [32s, 32s+32)) — two b128
      const uint4* hp = (const uint4*)hb8 + ((j & 1) << 4) + (s << 1);
      uint4 hv0 = hp[0], hv1 = hp[1];

      int a0, a1, a2, a3, a4, a5, a6, a7;
#define DOTSLOT(A, T)                                             \
      A = sdot4(w[2*T+1].w, hv1.w,                                \
          sdot4(w[2*T+1].z, hv1.z,                                \
          sdot4(w[2*T+1].y, hv1.y,                                \
          sdot4(w[2*T+1].x, hv1.x,                                \
          sdot4(w[2*T].w,   hv0.w,                                \
          sdot4(w[2*T].z,   hv0.z,                                \
          sdot4(w[2*T].y,   hv0.y,                                \
          sdot4(w[2*T].x,   hv0.x, 0))))))));
      DOTSLOT(a0, 0) DOTSLOT(a1, 1) DOTSLOT(a2, 2) DOTSLOT(a3, 3)
      DOTSLOT(a4, 4) DOTSLOT(a5, 5) DOTSLOT(a6, 6) DOTSLOT(a7, 7)
#undef DOTSLOT
      // 3-stage all-DPP butterfly (exact integer adds, bit-identical):
      // stage1 pairs slots {2j,2j+1} across lane^1; stage2 across lane^2;
      // stage3 across lane^8 (row_ror:8). Lane ends with full sum of row s.
      int b0 = a0 + dpp_xor1(a1);
      int b1 = a2 + dpp_xor1(a3);
      int b2 = a4 + dpp_xor1(a5);
      int b3 = a6 + dpp_xor1(a7);
      int c0 = b0 + dpp_xor2(b1);
      int c1 = b2 + dpp_xor2(b3);
      int e  = c0 + dpp_ror8(c1);

      float xarg = __builtin_fmaf((float)e, kk, xbs);
      float r = __builtin_amdgcn_rcpf(1.0f + __builtin_amdgcn_exp2f(xarg));
      float g = __builtin_fmaf(aa, r, bb);  // own activated gate
      float gi = dpp_bcastf<0x00>(g);
      float gf = dpp_bcastf<0x55>(g);
      float gg = dpp_bcastf<0xAA>(g);
      float go = dpp_bcastf<0xFF>(g);
      c_state = __builtin_fmaf(gf, c_state, gi * gg);
      float h = go * tanhf_fast(c_state);
      int q8 = (int)rintf(h * 127.0f);
      if ((l & 3) == 0) {  // quad leader owns unit u_own
        hb8[(j & 1) ^ 1][u_own] = (unsigned char)(q8 & 0xff);
        if (h_full) *hout = (f16)h;
        if (HASMAP && ms >= 0) h1g[(size_t)ms * 512 + (dir << 8) + u_own] = (f16)h;
      }
      wg_barrier_lds();  // LDS-only wait; global ops stay in flight
      t += tstep;
      hout += hstride;
    }
    xcur = xnxt;
  }
}

// ---------------- FC + gather ----------------
// mapn == null: slot = idx[n] (dense h layout); else slot = mapn[idx[n]].
__global__ void k_fc(const f16* __restrict__ hbase, const int* __restrict__ mapn,
                     const int* __restrict__ idx, const float* __restrict__ fcw,
                     void* __restrict__ out, const u32* __restrict__ dtp) {
  u32 isf = *dtp;
  int n = blockIdx.x;
  int cc = threadIdx.x;  // 64
  int slot = mapn ? mapn[idx[n]] : idx[n];
  const f16* hp = hbase + (size_t)slot * 512;
  float acc = 0.f;
#pragma unroll 8
  for (int k = 0; k < 512; ++k) acc += (float)hp[k] * fcw[k * 64 + cc];
  int o = (cc < 32) ? (n * 32 + cc) : (32 * 1024 + n * 32 + (cc - 32));
  if (isf) ((float*)out)[o] = acc;
  else     ((u16*)out)[o]   = f2bf(acc);
}

// ---------------- launch ----------------
extern "C" void kernel_launch(void* const* d_in, const int* in_sizes, int n_in,
                              void* d_out, int out_size, void* d_ws, size_t ws_size,
                              hipStream_t stream) {
  const void* Y        = d_in[0];
  const void* dT       = d_in[1];
  const int*  idx      = (const int*)d_in[2];
  const void* w_ih_l0f = d_in[3];
  const void* w_hh_l0f = d_in[4];
  const void* b_ih_l0f = d_in[5];
  const void* b_hh_l0f = d_in[6];
  const void* w_ih_l0b = d_in[7];
  const void* w_hh_l0b = d_in[8];
  const void* b_ih_l0b = d_in[9];
  const void* b_hh_l0b = d_in[10];
  const void* w_ih_l1f = d_in[11];
  const void* w_hh_l1f = d_in[12];
  const void* b_ih_l1f = d_in[13];
  const void* b_hh_l1f = d_in[14];
  const void* w_ih_l1b = d_in[15];
  const void* w_hh_l1b = d_in[16];
  const void* b_ih_l1b = d_in[17];
  const void* b_hh_l1b = d_in[18];
  const void* fcbf     = d_in[19];

  char* ws = (char*)d_ws;
  u32*  dt    = (u32*)(ws + OFF_DT);
  u32*  flags = (u32*)(ws + OFF_FLG);
  int*  map   = (int*)(ws + OFF_MAP);
  f16*  h1g   = (f16*)(ws + OFF_H1G);
  float* bias = (float*)(ws + OFF_BIAS);
  float* fcw  = (float*)(ws + OFF_FCW);
  u32*  wq8   = (u32*)(ws + OFF_WQ8);
  u32*  wih0  = (u32*)(ws + OFF_WIH0);
  u32*  wih1  = (u32*)(ws + OFF_WIH1);
  u32*  xq    = (u32*)(ws + OFF_XQ);
  f16*  h0    = (f16*)(ws + OFF_H0);
  f16*  xg    = (f16*)(ws + OFF_XG);
  f16*  xg1   = xg + XG_DIR / 2;  // f16 elements

  const int par = (ws_size >= NEED_PAR) ? 1 : 0;

  k_detect<<<1, 256, 0, stream>>>((const u16*)w_hh_l0f, dt);
  k_quant<<<256, 256, 0, stream>>>(w_hh_l0f, wq8 + 0 * 65536, dt);
  k_quant<<<256, 256, 0, stream>>>(w_hh_l0b, wq8 + 1 * 65536, dt);
  k_quant<<<256, 256, 0, stream>>>(w_hh_l1f, wq8 + 2 * 65536, dt);
  k_quant<<<256, 256, 0, stream>>>(w_hh_l1b, wq8 + 3 * 65536, dt);
  k_conv_pairs<<<128, 256, 0, stream>>>(w_ih_l0f, wih0 + 0, 32768, dt);
  k_conv_pairs<<<128, 256, 0, stream>>>(w_ih_l0b, wih0 + 32768, 32768, dt);
  k_conv_pairs<<<1024, 256, 0, stream>>>(w_ih_l1f, wih1 + 0, 262144, dt);
  k_conv_pairs<<<1024, 256, 0, stream>>>(w_ih_l1b, wih1 + 262144, 262144, dt);
  k_conv_misc<<<273, 256, 0, stream>>>(b_ih_l0f, b_hh_l0f, b_ih_l0b, b_hh_l0b,
                                       b_ih_l1f, b_hh_l1f, b_ih_l1b, b_hh_l1b,
                                       fcbf, bias, fcw, flags, map, dt);
  k_conv_x<<<4096, 256, 0, stream>>>(Y, dT, xq, dt);
  k_map_set<<<4, 256, 0, stream>>>(idx, map);

  dim3 ggrid(T_SEQ / 64, 16);
  if (par) {
    k_gemm<<<ggrid, 256, 0, stream>>>(xq, wih0, bias, xg, 32, 0);
    k_gemm<<<ggrid, 256, 0, stream>>>(xq, wih0 + 32768, bias + 1024, xg1, 32, 1);
    k_recur2<false><<<2, 1024, 0, stream>>>(xg, wq8, h0, nullptr, nullptr, 0);
    k_gemm<<<ggrid, 256, 0, stream>>>((const u32*)h0, wih1, bias + 2048, xg, 256, 0);
    k_gemm<<<ggrid, 256, 0, stream>>>((const u32*)h0, wih1 + 262144, bias + 3072, xg1, 256, 1);
    // L1 writes dense h into h0 (free after the two gemms above); no map.
    k_recur2<false><<<2, 1024, 0, stream>>>(xg, wq8 + 2 * 65536, h0, nullptr, nullptr, 0);
    k_fc<<<1024, 64, 0, stream>>>(h0, nullptr, idx, fcw, d_out, dt);
  } else {
    k_gemm<<<ggrid, 256, 0, stream>>>(xq, wih0, bias, xg, 32, 0);
    k_recur2<false><<<1, 1024, 0, stream>>>(xg, wq8, h0, nullptr, nullptr, 0);
    k_gemm<<<ggrid, 256, 0, stream>>>(xq, wih0 + 32768, bias + 1024, xg, 32, 1);
    k_recur2<false><<<1, 1024, 0, stream>>>(xg, wq8, h0, nullptr, nullptr, 1);
    k_gemm<<<ggrid, 256, 0, stream>>>((const u32*)h0, wih1, bias + 2048, xg, 256, 0);
    k_recur2<true><<<1, 1024, 0, stream>>>(xg, wq8 + 2 * 65536, nullptr, h1g, map, 0);
    k_gemm<<<ggrid, 256, 0, stream>>>((const u32*)h0, wih1 + 262144, bias + 3072, xg, 256, 1);
    k_recur2<true><<<1, 1024, 0, stream>>>(xg, wq8 + 2 * 65536, nullptr, h1g, map, 1);
    k_fc<<<1024, 64, 0, stream>>>(h1g, map, idx, fcw, d_out, dt);
  }
}

// Round 7
// 55991.888 us; speedup vs baseline: 1.1000x; 1.0908x over previous
//
#include <hip/hip_runtime.h>

typedef unsigned int u32;
typedef unsigned short u16;
typedef _Float16 f16;
typedef _Float16 f16x2 __attribute__((ext_vector_type(2)));
typedef _Float16 f16x4 __attribute__((ext_vector_type(4)));

#define T_SEQ 32768

// ---------------- ws layout (bytes) ----------------
static const size_t OFF_DT   = 0;         // u32 dtype flag (1 = f32 inputs)
static const size_t OFF_FLG  = 1024;      // u32[128] (legacy, kept zeroed)
static const size_t OFF_MAP  = 4096;      // int [T]
static const size_t OFF_H1G  = 135168;    // f16 [1024][512]
static const size_t OFF_BIAS = 1183744;   // f32 [4][1024]
static const size_t OFF_FCW  = 1200128;   // f32 [512*64]
static const size_t OFF_WQ8  = 1331200;   // u32 [4][1024][64] int8 W_hh (1 MB)
static const size_t OFF_WIH0 = 3428352;   // u32 [2][1024][32]
static const size_t OFF_WIH1 = 3690496;   // u32 [2][1024][256]
static const size_t OFF_XQ   = 5787648;   // u32 [T][32]
static const size_t OFF_H0   = 9981952;   // f16 [T][512]
static const size_t OFF_XG   = 43536384;  // f16 xgT [ndir][1024][T], LAST
static const size_t XG_DIR   = (size_t)T_SEQ * 1024 * 2;  // 67108864 bytes
static const size_t NEED_PAR = OFF_XG + 2 * XG_DIR;       // 177754112

// ---------------- helpers ----------------
__device__ __forceinline__ float bf2f(u16 u) {
  union { u32 i; float f; } v; v.i = ((u32)u) << 16; return v.f;
}
__device__ __forceinline__ u16 f2bf(float f) {
  union { float f; u32 i; } v; v.f = f;
  u32 u = v.i;
  return (u16)((u + 0x7fffu + ((u >> 16) & 1u)) >> 16);
}
__device__ __forceinline__ u32 packf2(float a, float b) {
  f16x2 p; p.x = (f16)a; p.y = (f16)b;
  return __builtin_bit_cast(u32, p);
}
__device__ __forceinline__ u32 bf2f2(u32 v) {  // two bf16 -> two f16
  union { u32 i; float f; } lo, hi;
  lo.i = v << 16; hi.i = v & 0xffff0000u;
  return packf2(lo.f, hi.f);
}
__device__ __forceinline__ float ldf(const void* p, size_t i, u32 isf) {
  return isf ? ((const float*)p)[i] : bf2f(((const u16*)p)[i]);
}
__device__ __forceinline__ float fdot2f(f16x2 a, f16x2 b, float c) {
#if __has_builtin(__builtin_amdgcn_fdot2)
  return __builtin_amdgcn_fdot2(a, b, c, false);
#else
  return c + (float)a.x * (float)b.x + (float)a.y * (float)b.y;
#endif
}
__device__ __forceinline__ float fdotu(u32 a, u32 b, float c) {
  return fdot2f(__builtin_bit_cast(f16x2, a), __builtin_bit_cast(f16x2, b), c);
}
__device__ __forceinline__ int sdot4(u32 a, u32 b, int c) {
#if __has_builtin(__builtin_amdgcn_sdot4)
  return __builtin_amdgcn_sdot4((int)a, (int)b, c, false);
#else
  int r = c;
#pragma unroll
  for (int j = 0; j < 4; ++j)
    r += (int)(signed char)(a >> (8 * j)) * (int)(signed char)(b >> (8 * j));
  return r;
#endif
}
// lane permutes: all VALU DPP (no LDS pipe in the per-step chain).
__device__ __forceinline__ int dpp_xor1(int x) {  // quad_perm [1,0,3,2]
#if __has_builtin(__builtin_amdgcn_update_dpp)
  return __builtin_amdgcn_update_dpp(0, x, 0xB1, 0xF, 0xF, true);
#else
  return __shfl_xor(x, 1);
#endif
}
__device__ __forceinline__ int dpp_xor2(int x) {  // quad_perm [2,3,0,1]
#if __has_builtin(__builtin_amdgcn_update_dpp)
  return __builtin_amdgcn_update_dpp(0, x, 0x4E, 0xF, 0xF, true);
#else
  return __shfl_xor(x, 2);
#endif
}
__device__ __forceinline__ int dpp_ror8(int x) {  // row_ror:8 == lane^8 in row16
#if __has_builtin(__builtin_amdgcn_update_dpp)
  return __builtin_amdgcn_update_dpp(0, x, 0x128, 0xF, 0xF, true);
#else
  return __shfl_xor(x, 8);
#endif
}
template <int CTRL>
__device__ __forceinline__ float dpp_bcastf(float x) {  // quad broadcast
#if __has_builtin(__builtin_amdgcn_update_dpp)
  return __builtin_bit_cast(float,
      __builtin_amdgcn_update_dpp(0, __builtin_bit_cast(int, x), CTRL, 0xF, 0xF, true));
#else
  return __shfl(x, (threadIdx.x & ~3) + (CTRL & 3));
#endif
}
__device__ __forceinline__ float tanhf_fast(float x) {
  return 1.0f - 2.0f * __builtin_amdgcn_rcpf(1.0f + __builtin_amdgcn_exp2f(2.8853900817779268f * x));
}
// raw workgroup barrier WITHOUT the vmcnt(0) drain __syncthreads imposes:
// only LDS (lgkmcnt) ordering is needed for the h-byte exchange; global
// loads/stores stay in flight across the barrier.
__device__ __forceinline__ void wg_barrier_lds() {
  asm volatile("s_waitcnt lgkmcnt(0)" ::: "memory");
  __builtin_amdgcn_s_barrier();
  asm volatile("" ::: "memory");
}

// ---------------- dtype detection ----------------
__global__ void k_detect(const u16* __restrict__ probe, u32* __restrict__ dt) {
  __shared__ int cnt;
  if (threadIdx.x == 0) cnt = 0;
  __syncthreads();
  int bad = 0;
  for (int i = threadIdx.x; i < 8192; i += 256) {
    float v = bf2f(probe[i]);
    if (!(v * v <= 16.0f)) bad++;
  }
  atomicAdd(&cnt, bad);
  __syncthreads();
  if (threadIdx.x == 0) *dt = (cnt > 64) ? 1u : 0u;
}

// ---------------- conversions ----------------
__global__ void k_conv_pairs(const void* __restrict__ src, u32* __restrict__ dst,
                             int np, const u32* __restrict__ dtp) {
  u32 isf = *dtp;
  int i = blockIdx.x * 256 + threadIdx.x;
  if (i >= np) return;
  if (isf) {
    const float* s = (const float*)src;
    dst[i] = packf2(s[2 * i], s[2 * i + 1]);
  } else {
    dst[i] = bf2f2(((const u32*)src)[i]);
  }
}

// int8-quantize one W_hh matrix [1024][256] -> u32 [1024][64], scale 2048
__global__ void k_quant(const void* __restrict__ src, u32* __restrict__ dst,
                        const u32* __restrict__ dtp) {
  u32 isf = *dtp;
  int i = blockIdx.x * 256 + threadIdx.x;  // 65536
  int row = i >> 6, c = i & 63;
  u32 out = 0;
#pragma unroll
  for (int j = 0; j < 4; ++j) {
    float w = ldf(src, (size_t)row * 256 + 4 * c + j, isf);
    int q = (int)rintf(w * 2048.0f);
    q = q > 127 ? 127 : (q < -127 ? -127 : q);
    out |= ((u32)(q & 0xff)) << (8 * j);
  }
  dst[i] = out;
}

__global__ void k_conv_misc(const void* bi0f, const void* bh0f, const void* bi0b, const void* bh0b,
                            const void* bi1f, const void* bh1f, const void* bi1b, const void* bh1b,
                            const void* fcb, float* __restrict__ bias, float* __restrict__ fcw,
                            u32* __restrict__ flags, int* __restrict__ map,
                            const u32* __restrict__ dtp) {
  u32 isf = *dtp;
  int i = blockIdx.x * 256 + threadIdx.x;
  if (i < 4096) {
    int ld = i >> 10, r = i & 1023;
    const void* bi; const void* bh;
    if (ld == 0)      { bi = bi0f; bh = bh0f; }
    else if (ld == 1) { bi = bi0b; bh = bh0b; }
    else if (ld == 2) { bi = bi1f; bh = bh1f; }
    else              { bi = bi1b; bh = bh1b; }
    bias[i] = ldf(bi, r, isf) + ldf(bh, r, isf);
  } else if (i < 36864) {
    fcw[i - 4096] = ldf(fcb, i - 4096, isf);
  } else if (i < 36992) {
    flags[i - 36864] = 0;
  } else if (i < 69760) {
    map[i - 36992] = -1;
  }
}

__global__ void k_conv_x(const void* __restrict__ Y, const void* __restrict__ dT,
                         u32* __restrict__ xq, const u32* __restrict__ dtp) {
  u32 isf = *dtp;
  int i = blockIdx.x * 256 + threadIdx.x;  // T*32
  if (i >= T_SEQ * 32) return;
  int t = i >> 5, m = i & 31, k2 = 2 * m;
  float a = ldf(Y, (size_t)t * 63 + k2, isf);
  float b = (k2 + 1 < 63) ? ldf(Y, (size_t)t * 63 + k2 + 1, isf) : ldf(dT, t, isf);
  xq[i] = packf2(a, b);
}

__global__ void k_map_set(const int* __restrict__ idx, int* __restrict__ map) {
  int i = blockIdx.x * 256 + threadIdx.x;
  if (i < 1024) map[idx[i]] = i;
}

// ---------------- input-projection GEMM ----------------
// Writes xg TRANSPOSED: xgT[row r][time t], with t-REVERSED storage when
// rev=1 so the recurrence always streams ascending addresses.
__global__ __launch_bounds__(256) void k_gemm(
    const u32* __restrict__ Aq, const u32* __restrict__ Wc,
    const float* __restrict__ bias, f16* __restrict__ xgT, int Kp, int rev) {
  int t0 = blockIdx.x << 6, r0 = blockIdx.y << 6;
  int tid = threadIdx.x, tx = tid & 15, ty = tid >> 4;
  __shared__ u32 As[64][33];
  __shared__ u32 Bs[64][33];
  float acc[4][4] = {};
  for (int kp0 = 0; kp0 < Kp; kp0 += 32) {
#pragma unroll
    for (int i = 0; i < 8; ++i) {
      int idx = tid + (i << 8);
      int row = idx >> 5, kp = idx & 31, kpg = kp0 + kp;
      As[row][kp] = Aq[(size_t)(t0 + row) * Kp + kpg];
      Bs[row][kp] = Wc[(size_t)(r0 + row) * Kp + kpg];
    }
    __syncthreads();
#pragma unroll 4
    for (int kk = 0; kk < 32; ++kk) {
      u32 av[4], bv[4];
#pragma unroll
      for (int i = 0; i < 4; ++i) av[i] = As[ty * 4 + i][kk];
#pragma unroll
      for (int i = 0; i < 4; ++i) bv[i] = Bs[tx * 4 + i][kk];
#pragma unroll
      for (int i = 0; i < 4; ++i)
#pragma unroll
        for (int j = 0; j < 4; ++j)
          acc[i][j] = fdotu(av[i], bv[j], acc[i][j]);
    }
    __syncthreads();
  }
  int tb = t0 + (ty << 2);
#pragma unroll
  for (int j = 0; j < 4; ++j) {
    int rr = r0 + tx * 4 + j;
    float b = bias[rr];
    f16 v0 = (f16)(acc[0][j] + b);
    f16 v1 = (f16)(acc[1][j] + b);
    f16 v2 = (f16)(acc[2][j] + b);
    f16 v3 = (f16)(acc[3][j] + b);
    size_t base = (size_t)rr * T_SEQ;
    f16x4 v;
    size_t pos;
    if (rev) { pos = base + (size_t)(T_SEQ - 4 - tb); v = (f16x4){v3, v2, v1, v0}; }
    else     { pos = base + (size_t)tb;               v = (f16x4){v0, v1, v2, v3}; }
    *(f16x4*)(xgT + pos) = v;
  }
}

// ---------------- recurrence v7 ------------------------------------------
// 512 threads (8 waves), 8-way K-split, all-DPP butterfly — v6's math with
// HALF the waves per barrier. R3-R6 (all 16-wave) were flat across 2x static
// instruction changes => lockstep latency + 16-wave barrier rendezvous
// dominates, not issue. Halving wave count halves the rendezvous cost and
// the per-step issue only rises 692 vs 832 cyc/SIMD.
// Lane l (in-wave): s = (l&3)|((l>>1)&4) indexes an 8-lane XOR group
// (distances {1,2,8} = quad_perm xor1/xor2 + row_ror:8, all VALU DPP).
// Each group owns FOUR units = two 8-row sets (A: units ubase..+1,
// B: units ubase+2..+3). Slot t of set X holds row (t^s) of set X over
// K-chunk s (8 dwords). After the 3-stage butterfly per set, lane l holds
// gate (s&3) of unit ubase+(s>>2) [A] and unit ubase+2+(s>>2) [B]; the
// quad-broadcast + c_state update runs twice. 128 weight dwords/thread;
// __launch_bounds__(512,2) => 256-reg budget, no spill.
template <bool HASMAP>
__global__ __launch_bounds__(512, 2) void k_recur2(
    const f16* __restrict__ xgT, const u32* __restrict__ wq,
    f16* __restrict__ h_full, f16* __restrict__ h1g,
    const int* __restrict__ map, int dir0) {
  const int dir = dir0 + blockIdx.x;
  const int tid = threadIdx.x;
  const int l = tid & 63, wv = tid >> 6;          // 8 waves
  const int r16 = l >> 4, gbit = (l >> 2) & 1;
  const int s = (l & 3) | ((l >> 1) & 4);         // position in 8-lane group
  const int ubase = (((wv << 3) | (r16 << 1) | gbit) << 2);  // 4 units/group
  const int uA = ubase + (s >> 2);                // unit of set-A final row
  const int uB = uA + 2;                          // unit of set-B final row
  const u32* wqd = wq + ((size_t)dir << 16);      // [1024][64]

  __shared__ __align__(16) unsigned char hb8[2][256];  // double-buffered h (i8)

  // weights: set X slot t -> row (t^s) of set X, K-dwords [8s,8s+8).
  uint4 wA[16], wB[16];
  {
    const uint4* pw = (const uint4*)wqd;  // row stride = 16 uint4
#pragma unroll
    for (int t = 0; t < 8; ++t) {
      int rho = t ^ s;
      int RA = ((rho & 3) << 8) | (ubase + (rho >> 2));
      int RB = ((rho & 3) << 8) | (ubase + 2 + (rho >> 2));
      wA[2 * t]     = pw[(size_t)RA * 16 + 2 * s];
      wA[2 * t + 1] = pw[(size_t)RA * 16 + 2 * s + 1];
      wB[2 * t]     = pw[(size_t)RB * 16 + 2 * s];
      wB[2 * t + 1] = pw[(size_t)RB * 16 + 2 * s + 1];
    }
  }

  if (tid < 128) ((u32*)hb8)[tid] = 0;

  const float ksc = 1.0f / (2048.0f * 127.0f);
  // per-lane activation params: sigmoid for gates i,f,o; tanh for gate g(=2)
  const float sk = ((s & 3) == 2) ? 2.8853900817779268f : -1.4426950408889634f;
  const float aa = ((s & 3) == 2) ? -2.0f : 1.0f;
  const float bb = ((s & 3) == 2) ? 1.0f : 0.0f;
  const float kk = sk * ksc;  // fold the activation scale into the dot scale

  const f16* xg_d = xgT + (size_t)blockIdx.x * ((size_t)T_SEQ * 1024);
  const f16* xrowA = xg_d + (size_t)(((s & 3) << 8) | uA) * T_SEQ;
  const f16* xrowB = xg_d + (size_t)(((s & 3) << 8) | uB) * T_SEQ;

  const int tstep = dir ? -1 : 1;
  int t = dir ? (T_SEQ - 1) : 0;
  int mp = HASMAP ? map[t] : -1;
  float cA = 0.f, cB = 0.f;

  // incremental h-output pointer (valid only when h_full != null); uB = uA+2
  f16* hout = h_full ? (h_full + (size_t)t * 512 + (dir << 8) + uA) : nullptr;
  const ptrdiff_t hstride = (ptrdiff_t)tstep * 512;

  uint4 xcurA = *(const uint4*)xrowA;  // steps 0..7 of own gate, set A
  uint4 xcurB = *(const uint4*)xrowB;
  uint4 xnxtA = xcurA, xnxtB = xcurB;

  __syncthreads();  // hb8 zero visible (full drain once, outside the loop)

  for (int ch = 0; ch < T_SEQ / 8; ++ch) {
    if (ch + 1 < T_SEQ / 8) {
      xnxtA = *(const uint4*)(xrowA + (((size_t)ch + 1) << 3));
      xnxtB = *(const uint4*)(xrowB + (((size_t)ch + 1) << 3));
    }
#pragma unroll
    for (int j = 0; j < 8; ++j) {
      // own-gate pre-activation inputs (static extract, off the chain)
      u32 dwA = (j >> 1) == 0 ? xcurA.x : (j >> 1) == 1 ? xcurA.y
              : (j >> 1) == 2 ? xcurA.z : xcurA.w;
      u32 dwB = (j >> 1) == 0 ? xcurB.x : (j >> 1) == 1 ? xcurB.y
              : (j >> 1) == 2 ? xcurB.z : xcurB.w;
      f16x2 prA = __builtin_bit_cast(f16x2, dwA);
      f16x2 prB = __builtin_bit_cast(f16x2, dwB);
      float xbsA = sk * (float)((j & 1) ? prA.y : prA.x);
      float xbsB = sk * (float)((j & 1) ? prB.y : prB.x);

      int ms = mp;
      if (HASMAP) {  // seq-mode only: prefetch next map slot
        int tn = t + tstep;
        int idx2 = ((unsigned)tn < T_SEQ) ? tn : t;
        mp = map[idx2];
      }

      // this lane's 32 h-bytes (K [32s, 32s+32)) — two b128, shared by sets
      const uint4* hp = (const uint4*)hb8 + ((j & 1) << 4) + (s << 1);
      uint4 hv0 = hp[0], hv1 = hp[1];

      int a0, a1, a2, a3, a4, a5, a6, a7;
      int g0, g1, g2, g3, g4, g5, g6, g7;
#define DOTSLOT(A, W, T)                                          \
      A = sdot4(W[2*T+1].w, hv1.w,                                \
          sdot4(W[2*T+1].z, hv1.z,                                \
          sdot4(W[2*T+1].y, hv1.y,                                \
          sdot4(W[2*T+1].x, hv1.x,                                \
          sdot4(W[2*T].w,   hv0.w,                                \
          sdot4(W[2*T].z,   hv0.z,                                \
          sdot4(W[2*T].y,   hv0.y,                                \
          sdot4(W[2*T].x,   hv0.x, 0))))))));
      DOTSLOT(a0, wA, 0) DOTSLOT(a1, wA, 1) DOTSLOT(a2, wA, 2) DOTSLOT(a3, wA, 3)
      DOTSLOT(a4, wA, 4) DOTSLOT(a5, wA, 5) DOTSLOT(a6, wA, 6) DOTSLOT(a7, wA, 7)
      DOTSLOT(g0, wB, 0) DOTSLOT(g1, wB, 1) DOTSLOT(g2, wB, 2) DOTSLOT(g3, wB, 3)
      DOTSLOT(g4, wB, 4) DOTSLOT(g5, wB, 5) DOTSLOT(g6, wB, 6) DOTSLOT(g7, wB, 7)
#undef DOTSLOT
      // 3-stage all-DPP butterfly per set (exact integer adds):
      int bA0 = a0 + dpp_xor1(a1);
      int bA1 = a2 + dpp_xor1(a3);
      int bA2 = a4 + dpp_xor1(a5);
      int bA3 = a6 + dpp_xor1(a7);
      int cA0 = bA0 + dpp_xor2(bA1);
      int cA1 = bA2 + dpp_xor2(bA3);
      int eA  = cA0 + dpp_ror8(cA1);
      int bB0 = g0 + dpp_xor1(g1);
      int bB1 = g2 + dpp_xor1(g3);
      int bB2 = g4 + dpp_xor1(g5);
      int bB3 = g6 + dpp_xor1(g7);
      int cB0 = bB0 + dpp_xor2(bB1);
      int cB1 = bB2 + dpp_xor2(bB3);
      int eB  = cB0 + dpp_ror8(cB1);

      // set A: activation + state
      float xargA = __builtin_fmaf((float)eA, kk, xbsA);
      float rA = __builtin_amdgcn_rcpf(1.0f + __builtin_amdgcn_exp2f(xargA));
      float gA = __builtin_fmaf(aa, rA, bb);
      float giA = dpp_bcastf<0x00>(gA);
      float gfA = dpp_bcastf<0x55>(gA);
      float ggA = dpp_bcastf<0xAA>(gA);
      float goA = dpp_bcastf<0xFF>(gA);
      cA = __builtin_fmaf(gfA, cA, giA * ggA);
      float hA = goA * tanhf_fast(cA);
      int qA = (int)rintf(hA * 127.0f);
      // set B: activation + state
      float xargB = __builtin_fmaf((float)eB, kk, xbsB);
      float rB = __builtin_amdgcn_rcpf(1.0f + __builtin_amdgcn_exp2f(xargB));
      float gB = __builtin_fmaf(aa, rB, bb);
      float giB = dpp_bcastf<0x00>(gB);
      float gfB = dpp_bcastf<0x55>(gB);
      float ggB = dpp_bcastf<0xAA>(gB);
      float goB = dpp_bcastf<0xFF>(gB);
      cB = __builtin_fmaf(gfB, cB, giB * ggB);
      float hB = goB * tanhf_fast(cB);
      int qB = (int)rintf(hB * 127.0f);

      if ((l & 3) == 0) {  // quad leader owns units uA, uB
        hb8[(j & 1) ^ 1][uA] = (unsigned char)(qA & 0xff);
        hb8[(j & 1) ^ 1][uB] = (unsigned char)(qB & 0xff);
        if (h_full) { hout[0] = (f16)hA; hout[2] = (f16)hB; }
        if (HASMAP && ms >= 0) {
          f16* hg = h1g + (size_t)ms * 512 + (dir << 8) + uA;
          hg[0] = (f16)hA; hg[2] = (f16)hB;
        }
      }
      wg_barrier_lds();  // LDS-only wait; global ops stay in flight
      t += tstep;
      hout += hstride;
    }
    xcurA = xnxtA;
    xcurB = xnxtB;
  }
}

// ---------------- FC + gather ----------------
// mapn == null: slot = idx[n] (dense h layout); else slot = mapn[idx[n]].
__global__ void k_fc(const f16* __restrict__ hbase, const int* __restrict__ mapn,
                     const int* __restrict__ idx, const float* __restrict__ fcw,
                     void* __restrict__ out, const u32* __restrict__ dtp) {
  u32 isf = *dtp;
  int n = blockIdx.x;
  int cc = threadIdx.x;  // 64
  int slot = mapn ? mapn[idx[n]] : idx[n];
  const f16* hp = hbase + (size_t)slot * 512;
  float acc = 0.f;
#pragma unroll 8
  for (int k = 0; k < 512; ++k) acc += (float)hp[k] * fcw[k * 64 + cc];
  int o = (cc < 32) ? (n * 32 + cc) : (32 * 1024 + n * 32 + (cc - 32));
  if (isf) ((float*)out)[o] = acc;
  else     ((u16*)out)[o]   = f2bf(acc);
}

// ---------------- launch ----------------
extern "C" void kernel_launch(void* const* d_in, const int* in_sizes, int n_in,
                              void* d_out, int out_size, void* d_ws, size_t ws_size,
                              hipStream_t stream) {
  const void* Y        = d_in[0];
  const void* dT       = d_in[1];
  const int*  idx      = (const int*)d_in[2];
  const void* w_ih_l0f = d_in[3];
  const void* w_hh_l0f = d_in[4];
  const void* b_ih_l0f = d_in[5];
  const void* b_hh_l0f = d_in[6];
  const void* w_ih_l0b = d_in[7];
  const void* w_hh_l0b = d_in[8];
  const void* b_ih_l0b = d_in[9];
  const void* b_hh_l0b = d_in[10];
  const void* w_ih_l1f = d_in[11];
  const void* w_hh_l1f = d_in[12];
  const void* b_ih_l1f = d_in[13];
  const void* b_hh_l1f = d_in[14];
  const void* w_ih_l1b = d_in[15];
  const void* w_hh_l1b = d_in[16];
  const void* b_ih_l1b = d_in[17];
  const void* b_hh_l1b = d_in[18];
  const void* fcbf     = d_in[19];

  char* ws = (char*)d_ws;
  u32*  dt    = (u32*)(ws + OFF_DT);
  u32*  flags = (u32*)(ws + OFF_FLG);
  int*  map   = (int*)(ws + OFF_MAP);
  f16*  h1g   = (f16*)(ws + OFF_H1G);
  float* bias = (float*)(ws + OFF_BIAS);
  float* fcw  = (float*)(ws + OFF_FCW);
  u32*  wq8   = (u32*)(ws + OFF_WQ8);
  u32*  wih0  = (u32*)(ws + OFF_WIH0);
  u32*  wih1  = (u32*)(ws + OFF_WIH1);
  u32*  xq    = (u32*)(ws + OFF_XQ);
  f16*  h0    = (f16*)(ws + OFF_H0);
  f16*  xg    = (f16*)(ws + OFF_XG);
  f16*  xg1   = xg + XG_DIR / 2;  // f16 elements

  const int par = (ws_size >= NEED_PAR) ? 1 : 0;

  k_detect<<<1, 256, 0, stream>>>((const u16*)w_hh_l0f, dt);
  k_quant<<<256, 256, 0, stream>>>(w_hh_l0f, wq8 + 0 * 65536, dt);
  k_quant<<<256, 256, 0, stream>>>(w_hh_l0b, wq8 + 1 * 65536, dt);
  k_quant<<<256, 256, 0, stream>>>(w_hh_l1f, wq8 + 2 * 65536, dt);
  k_quant<<<256, 256, 0, stream>>>(w_hh_l1b, wq8 + 3 * 65536, dt);
  k_conv_pairs<<<128, 256, 0, stream>>>(w_ih_l0f, wih0 + 0, 32768, dt);
  k_conv_pairs<<<128, 256, 0, stream>>>(w_ih_l0b, wih0 + 32768, 32768, dt);
  k_conv_pairs<<<1024, 256, 0, stream>>>(w_ih_l1f, wih1 + 0, 262144, dt);
  k_conv_pairs<<<1024, 256, 0, stream>>>(w_ih_l1b, wih1 + 262144, 262144, dt);
  k_conv_misc<<<273, 256, 0, stream>>>(b_ih_l0f, b_hh_l0f, b_ih_l0b, b_hh_l0b,
                                       b_ih_l1f, b_hh_l1f, b_ih_l1b, b_hh_l1b,
                                       fcbf, bias, fcw, flags, map, dt);
  k_conv_x<<<4096, 256, 0, stream>>>(Y, dT, xq, dt);
  k_map_set<<<4, 256, 0, stream>>>(idx, map);

  dim3 ggrid(T_SEQ / 64, 16);
  if (par) {
    k_gemm<<<ggrid, 256, 0, stream>>>(xq, wih0, bias, xg, 32, 0);
    k_gemm<<<ggrid, 256, 0, stream>>>(xq, wih0 + 32768, bias + 1024, xg1, 32, 1);
    k_recur2<false><<<2, 512, 0, stream>>>(xg, wq8, h0, nullptr, nullptr, 0);
    k_gemm<<<ggrid, 256, 0, stream>>>((const u32*)h0, wih1, bias + 2048, xg, 256, 0);
    k_gemm<<<ggrid, 256, 0, stream>>>((const u32*)h0, wih1 + 262144, bias + 3072, xg1, 256, 1);
    // L1 writes dense h into h0 (free after the two gemms above); no map.
    k_recur2<false><<<2, 512, 0, stream>>>(xg, wq8 + 2 * 65536, h0, nullptr, nullptr, 0);
    k_fc<<<1024, 64, 0, stream>>>(h0, nullptr, idx, fcw, d_out, dt);
  } else {
    k_gemm<<<ggrid, 256, 0, stream>>>(xq, wih0, bias, xg, 32, 0);
    k_recur2<false><<<1, 512, 0, stream>>>(xg, wq8, h0, nullptr, nullptr, 0);
    k_gemm<<<ggrid, 256, 0, stream>>>(xq, wih0 + 32768, bias + 1024, xg, 32, 1);
    k_recur2<false><<<1, 512, 0, stream>>>(xg, wq8, h0, nullptr, nullptr, 1);
    k_gemm<<<ggrid, 256, 0, stream>>>((const u32*)h0, wih1, bias + 2048, xg, 256, 0);
    k_recur2<true><<<1, 512, 0, stream>>>(xg, wq8 + 2 * 65536, nullptr, h1g, map, 0);
    k_gemm<<<ggrid, 256, 0, stream>>>((const u32*)h0, wih1 + 262144, bias + 3072, xg, 256, 1);
    k_recur2<true><<<1, 512, 0, stream>>>(xg, wq8 + 2 * 65536, nullptr, h1g, map, 1);
    k_fc<<<1024, 64, 0, stream>>>(h1g, map, idx, fcw, d_out, dt);
  }
}